// Round 1
// baseline (745.977 us; speedup 1.0000x reference)
//
#include <hip/hip_runtime.h>

typedef _Float16 f16;
typedef __attribute__((ext_vector_type(8))) _Float16 f16x8;
typedef __attribute__((ext_vector_type(4))) float f32x4;

#define LDK 40  // LDS row stride in f16 (80 B, keeps 16B alignment, breaks pow2 banks)

// ---- staging helpers: tile is 64 rows x 32 K-cols, 256 threads ----

__device__ __forceinline__ void stage_f32(const float* __restrict__ src, int ld, f16* dst) {
    int t = threadIdx.x;
    int row = t >> 2;
    int c0 = (t & 3) * 8;
    const float* p = src + (size_t)row * ld + c0;
    float4 u = *(const float4*)p;
    float4 w = *(const float4*)(p + 4);
    f16x8 h;
    h[0] = (f16)u.x; h[1] = (f16)u.y; h[2] = (f16)u.z; h[3] = (f16)u.w;
    h[4] = (f16)w.x; h[5] = (f16)w.y; h[6] = (f16)w.z; h[7] = (f16)w.w;
    *(f16x8*)(dst + row * LDK + c0) = h;
}

__device__ __forceinline__ void stage_f16g(const f16* __restrict__ src, int ld, f16* dst) {
    int t = threadIdx.x;
    int row = t >> 2;
    int c0 = (t & 3) * 8;
    *(f16x8*)(dst + row * LDK + c0) = *(const f16x8*)(src + (size_t)row * ld + c0);
}

// stage V tile (32 s-rows x 64 d) transposed into Bs[d][s]
__device__ __forceinline__ void stage_vT(const f16* __restrict__ src, f16* dst) {
    int t = threadIdx.x;
    int s = t >> 3;
    int d0 = (t & 7) * 8;
    f16x8 h = *(const f16x8*)(src + (size_t)s * 64 + d0);
#pragma unroll
    for (int j = 0; j < 8; ++j) dst[(d0 + j) * LDK + s] = h[j];
}

// ---- MFMA core: 4 waves, each computes 32x32 of a 64x64 C tile ----
// A-frag: A[m=lane&15][k=(lane>>4)*8 + j]; B-frag: B[n=lane&15][k=...]
// C/D:    D[m=(lane>>4)*4 + reg][n=lane&15]

__device__ __forceinline__ void mma_step(const f16* As, const f16* Bs, int m_off, int n_off,
                                         f32x4 acc[2][2]) {
    int lane = threadIdx.x & 63;
    int r = lane & 15;
    int kq = (lane >> 4) * 8;
    f16x8 a0 = *(const f16x8*)(As + (m_off + r) * LDK + kq);
    f16x8 a1 = *(const f16x8*)(As + (m_off + 16 + r) * LDK + kq);
    f16x8 b0 = *(const f16x8*)(Bs + (n_off + r) * LDK + kq);
    f16x8 b1 = *(const f16x8*)(Bs + (n_off + 16 + r) * LDK + kq);
    acc[0][0] = __builtin_amdgcn_mfma_f32_16x16x32_f16(a0, b0, acc[0][0], 0, 0, 0);
    acc[0][1] = __builtin_amdgcn_mfma_f32_16x16x32_f16(a0, b1, acc[0][1], 0, 0, 0);
    acc[1][0] = __builtin_amdgcn_mfma_f32_16x16x32_f16(a1, b0, acc[1][0], 0, 0, 0);
    acc[1][1] = __builtin_amdgcn_mfma_f32_16x16x32_f16(a1, b1, acc[1][1], 0, 0, 0);
}

#define GEMM_PROLOGUE()                                         \
    __shared__ f16 As[64 * LDK];                                \
    __shared__ f16 Bs[64 * LDK];                                \
    const int w = threadIdx.x >> 6;                             \
    const int m_off = (w & 1) * 32, n_off = (w >> 1) * 32;      \
    const int lane = threadIdx.x & 63;                          \
    f32x4 zero = {0.f, 0.f, 0.f, 0.f};                          \
    f32x4 acc[2][2] = {{zero, zero}, {zero, zero}};

// MODE 0: Q (writes q_u and q_v with biases), 1: K/V, 2: P (no bias)
template <int MODE>
__global__ __launch_bounds__(256) void proj_gemm(
    const float* __restrict__ A, const float* __restrict__ W,
    const float* __restrict__ bias, const float* __restrict__ pbu,
    const float* __restrict__ pbv, f16* __restrict__ o1, f16* __restrict__ o2) {
    GEMM_PROLOGUE();
    const int m0 = blockIdx.y * 64;
    const int n0 = blockIdx.x * 64;
    for (int k0 = 0; k0 < 1024; k0 += 32) {
        stage_f32(A + (size_t)m0 * 1024 + k0, 1024, As);
        stage_f32(W + (size_t)n0 * 1024 + k0, 1024, Bs);
        __syncthreads();
        mma_step(As, Bs, m_off, n_off, acc);
        __syncthreads();
    }
#pragma unroll
    for (int mt = 0; mt < 2; ++mt)
#pragma unroll
        for (int nt = 0; nt < 2; ++nt)
#pragma unroll
            for (int rr = 0; rr < 4; ++rr) {
                int m = m0 + m_off + mt * 16 + (lane >> 4) * 4 + rr;
                int n = n0 + n_off + nt * 16 + (lane & 15);
                float vv = acc[mt][nt][rr];
                if (MODE == 2) {
                    int h = n >> 6, d = n & 63;
                    o1[((size_t)h * 1024 + m) * 64 + d] = (f16)vv;
                } else {
                    float base = vv + bias[n];
                    int b = m >> 10, t = m & 1023, h = n >> 6, d = n & 63;
                    size_t idx = ((size_t)((b * 16 + h) * 1024 + t)) * 64 + d;
                    if (MODE == 0) {
                        o1[idx] = (f16)(base + pbu[n]);
                        o2[idx] = (f16)(base + pbv[n]);
                    } else {
                        o1[idx] = (f16)base;
                    }
                }
            }
}

// BD = q_v @ p[h]^T per (b,h); epilogue writes rel_shift-ed positions.
__global__ __launch_bounds__(256) void bd_gemm(const f16* __restrict__ qv,
                                               const f16* __restrict__ p,
                                               f16* __restrict__ bds) {
    GEMM_PROLOGUE();
    const int bh = blockIdx.z;
    const int h = bh & 15;
    const int m0 = blockIdx.y * 64, n0 = blockIdx.x * 64;
    const f16* Ab = qv + (size_t)bh * 65536;
    const f16* Bb = p + (size_t)h * 65536;
    for (int k0 = 0; k0 < 64; k0 += 32) {
        stage_f16g(Ab + (size_t)m0 * 64 + k0, 64, As);
        stage_f16g(Bb + (size_t)n0 * 64 + k0, 64, Bs);
        __syncthreads();
        mma_step(As, Bs, m_off, n_off, acc);
        __syncthreads();
    }
    f16* B0 = bds + (size_t)bh * 1048576;
#pragma unroll
    for (int mt = 0; mt < 2; ++mt)
#pragma unroll
        for (int nt = 0; nt < 2; ++nt)
#pragma unroll
            for (int rr = 0; rr < 4; ++rr) {
                int r = m0 + m_off + mt * 16 + (lane >> 4) * 4 + rr;
                int c = n0 + n_off + nt * 16 + (lane & 15);
                float vv = acc[mt][nt][rr];
                if (c >= 1023 - r) {
                    B0[(size_t)r * 1024 + (c + r - 1023)] = (f16)vv;
                } else if (r >= 1) {
                    B0[(size_t)(r - 1) * 1024 + (c + r + 1)] = (f16)vv;
                }
            }
}

// AC = q_u @ kh^T per (b,h); epilogue adds shifted-BD (diagonal j==i+1 is 0),
// scales by 1/sqrt(64), writes scores back in place.
__global__ __launch_bounds__(256) void ac_gemm(const f16* __restrict__ qu,
                                               const f16* __restrict__ kh,
                                               f16* __restrict__ bds) {
    GEMM_PROLOGUE();
    const int bh = blockIdx.z;
    const int m0 = blockIdx.y * 64, n0 = blockIdx.x * 64;
    const f16* Ab = qu + (size_t)bh * 65536;
    const f16* Bb = kh + (size_t)bh * 65536;
    for (int k0 = 0; k0 < 64; k0 += 32) {
        stage_f16g(Ab + (size_t)m0 * 64 + k0, 64, As);
        stage_f16g(Bb + (size_t)n0 * 64 + k0, 64, Bs);
        __syncthreads();
        mma_step(As, Bs, m_off, n_off, acc);
        __syncthreads();
    }
#pragma unroll
    for (int mt = 0; mt < 2; ++mt)
#pragma unroll
        for (int nt = 0; nt < 2; ++nt)
#pragma unroll
            for (int rr = 0; rr < 4; ++rr) {
                int i = m0 + m_off + mt * 16 + (lane >> 4) * 4 + rr;
                int j = n0 + n_off + nt * 16 + (lane & 15);
                size_t idx = (size_t)bh * 1048576 + (size_t)i * 1024 + j;
                float bdv = (j == i + 1) ? 0.f : (float)bds[idx];
                bds[idx] = (f16)((acc[mt][nt][rr] + bdv) * 0.125f);
            }
}

// one block per score row: mask, max, exp, sum, normalize -> attn (fp32, d_out)
__global__ __launch_bounds__(256) void softmax_k(const f16* __restrict__ sp,
                                                 const int* __restrict__ mask,
                                                 float* __restrict__ attn) {
    const int row = blockIdx.x;  // bh*1024 + t
    const int bh = row >> 10, t = row & 1023;
    const int b = bh >> 4;
    const f16* s = sp + (size_t)row * 1024;
    const int* mk = mask + ((size_t)b * 1024 + t) * 1024;
    const int tid = threadIdx.x;
    float vals[4];
    float mx = -1e30f;
#pragma unroll
    for (int ii = 0; ii < 4; ++ii) {
        int c = tid + ii * 256;
        float v = (float)s[c];
        if (mk[c] == 0) v = -10000.0f;
        vals[ii] = v;
        mx = fmaxf(mx, v);
    }
#pragma unroll
    for (int off = 32; off > 0; off >>= 1) mx = fmaxf(mx, __shfl_xor(mx, off));
    __shared__ float red[4], red2[4];
    if ((tid & 63) == 0) red[tid >> 6] = mx;
    __syncthreads();
    mx = fmaxf(fmaxf(red[0], red[1]), fmaxf(red[2], red[3]));
    float sum = 0.f, e[4];
#pragma unroll
    for (int ii = 0; ii < 4; ++ii) {
        e[ii] = __expf(vals[ii] - mx);
        sum += e[ii];
    }
#pragma unroll
    for (int off = 32; off > 0; off >>= 1) sum += __shfl_xor(sum, off);
    if ((tid & 63) == 0) red2[tid >> 6] = sum;
    __syncthreads();
    sum = red2[0] + red2[1] + red2[2] + red2[3];
    float inv = 1.f / sum;
    float* arow = attn + (size_t)row * 1024;
#pragma unroll
    for (int ii = 0; ii < 4; ++ii) arow[tid + ii * 256] = e[ii] * inv;
}

// out_h = attn @ vh per (b,h); writes concat layout [b][t][h*64+d] as f16
__global__ __launch_bounds__(256) void pv_gemm(const float* __restrict__ attn,
                                               const f16* __restrict__ vh,
                                               f16* __restrict__ oh) {
    GEMM_PROLOGUE();
    const int bh = blockIdx.z;
    const int b = bh >> 4, h = bh & 15;
    const int m0 = blockIdx.y * 64;
    const float* Ab = attn + (size_t)bh * 1048576;
    const f16* Bb = vh + (size_t)bh * 65536;
    for (int k0 = 0; k0 < 1024; k0 += 32) {
        stage_f32(Ab + (size_t)m0 * 1024 + k0, 1024, As);
        stage_vT(Bb + (size_t)k0 * 64, Bs);
        __syncthreads();
        mma_step(As, Bs, m_off, n_off, acc);
        __syncthreads();
    }
#pragma unroll
    for (int mt = 0; mt < 2; ++mt)
#pragma unroll
        for (int nt = 0; nt < 2; ++nt)
#pragma unroll
            for (int rr = 0; rr < 4; ++rr) {
                int t = m0 + m_off + mt * 16 + (lane >> 4) * 4 + rr;
                int d = n_off + nt * 16 + (lane & 15);
                oh[((size_t)(b * 1024 + t)) * 1024 + h * 64 + d] =
                    (f16)acc[mt][nt][rr];
            }
}

// output = concat @ Wo^T + bo (fp32 out)
__global__ __launch_bounds__(256) void out_gemm(const f16* __restrict__ A,
                                                const float* __restrict__ W,
                                                const float* __restrict__ bias,
                                                float* __restrict__ out) {
    GEMM_PROLOGUE();
    const int m0 = blockIdx.y * 64;
    const int n0 = blockIdx.x * 64;
    for (int k0 = 0; k0 < 1024; k0 += 32) {
        stage_f16g(A + (size_t)m0 * 1024 + k0, 1024, As);
        stage_f32(W + (size_t)n0 * 1024 + k0, 1024, Bs);
        __syncthreads();
        mma_step(As, Bs, m_off, n_off, acc);
        __syncthreads();
    }
#pragma unroll
    for (int mt = 0; mt < 2; ++mt)
#pragma unroll
        for (int nt = 0; nt < 2; ++nt)
#pragma unroll
            for (int rr = 0; rr < 4; ++rr) {
                int m = m0 + m_off + mt * 16 + (lane >> 4) * 4 + rr;
                int n = n0 + n_off + nt * 16 + (lane & 15);
                out[(size_t)m * 1024 + n] = acc[mt][nt][rr] + bias[n];
            }
}

extern "C" void kernel_launch(void* const* d_in, const int* in_sizes, int n_in,
                              void* d_out, int out_size, void* d_ws, size_t ws_size,
                              hipStream_t stream) {
    (void)in_sizes; (void)n_in; (void)out_size; (void)ws_size;
    const float* q   = (const float*)d_in[0];
    const float* k   = (const float*)d_in[1];
    const float* v   = (const float*)d_in[2];
    const float* pe  = (const float*)d_in[3];
    const int*   msk = (const int*)d_in[4];
    const float* Wq  = (const float*)d_in[5];
    const float* bq  = (const float*)d_in[6];
    const float* Wk  = (const float*)d_in[7];
    const float* bk  = (const float*)d_in[8];
    const float* Wv  = (const float*)d_in[9];
    const float* bv  = (const float*)d_in[10];
    const float* Wp  = (const float*)d_in[11];
    const float* pbu = (const float*)d_in[12];
    const float* pbv = (const float*)d_in[13];
    const float* Wo  = (const float*)d_in[14];
    const float* bo  = (const float*)d_in[15];

    char* ws = (char*)d_ws;
    f16* q_u = (f16*)(ws + 0);          //  8 MB  [b][h][t][64]
    f16* q_v = (f16*)(ws + 8388608);    //  8 MB
    f16* kh  = (f16*)(ws + 16777216);   //  8 MB
    f16* vh  = (f16*)(ws + 25165824);   //  8 MB
    f16* pp  = (f16*)(ws + 33554432);   //  2 MB  [h][pos][64]
    f16* bds = (f16*)(ws + 35651584);   // 128 MB [b][h][t][s] (shifted BD, then scores)
    f16* oh  = (f16*)(ws + 169869312);  //  8 MB  [b][t][h*64+d]

    float* out  = (float*)d_out;
    float* attn = out + 4194304;

    dim3 blk(256);
    proj_gemm<0><<<dim3(16, 64), blk, 0, stream>>>(q, Wq, bq, pbu, pbv, q_u, q_v);
    proj_gemm<1><<<dim3(16, 64), blk, 0, stream>>>(k, Wk, bk, nullptr, nullptr, kh, nullptr);
    proj_gemm<1><<<dim3(16, 64), blk, 0, stream>>>(v, Wv, bv, nullptr, nullptr, vh, nullptr);
    proj_gemm<2><<<dim3(16, 16), blk, 0, stream>>>(pe, Wp, nullptr, nullptr, nullptr, pp, nullptr);
    bd_gemm<<<dim3(16, 16, 64), blk, 0, stream>>>(q_v, pp, bds);
    ac_gemm<<<dim3(16, 16, 64), blk, 0, stream>>>(q_u, kh, bds);
    softmax_k<<<dim3(65536), blk, 0, stream>>>(bds, msk, attn);
    pv_gemm<<<dim3(1, 16, 64), blk, 0, stream>>>(attn, vh, oh);
    out_gemm<<<dim3(16, 64), blk, 0, stream>>>(oh, Wo, bo, out);
}

// Round 2
// 703.844 us; speedup vs baseline: 1.0599x; 1.0599x over previous
//
#include <hip/hip_runtime.h>

typedef _Float16 f16;
typedef __attribute__((ext_vector_type(8))) _Float16 f16x8;
typedef __attribute__((ext_vector_type(4))) float f32x4;

#define LDK 40  // LDS row stride in f16 (80 B, 16B-aligned, breaks pow2 banks)

// ---- staging helpers: tile is 64 rows x 32 K-cols, 256 threads ----

__device__ __forceinline__ void stage_f16g(const f16* __restrict__ src, int ld, f16* dst) {
    int t = threadIdx.x;
    int row = t >> 2;
    int c0 = (t & 3) * 8;
    *(f16x8*)(dst + row * LDK + c0) = *(const f16x8*)(src + (size_t)row * ld + c0);
}

// stage V tile (32 s-rows x 64 d) transposed into Bs[d][s]
__device__ __forceinline__ void stage_vT(const f16* __restrict__ src, f16* dst) {
    int t = threadIdx.x;
    int s = t >> 3;
    int d0 = (t & 7) * 8;
    f16x8 h = *(const f16x8*)(src + (size_t)s * 64 + d0);
#pragma unroll
    for (int j = 0; j < 8; ++j) dst[(d0 + j) * LDK + s] = h[j];
}

// ---- MFMA core: 4 waves, each computes 32x32 of a 64x64 C tile ----
// A-frag: A[m=lane&15][k=(lane>>4)*8 + j]; B-frag: B[n=lane&15][k=...]
// C/D:    D[m=(lane>>4)*4 + reg][n=lane&15]

__device__ __forceinline__ void mma_step(const f16* As, const f16* Bs, int m_off, int n_off,
                                         f32x4 acc[2][2]) {
    int lane = threadIdx.x & 63;
    int r = lane & 15;
    int kq = (lane >> 4) * 8;
    f16x8 a0 = *(const f16x8*)(As + (m_off + r) * LDK + kq);
    f16x8 a1 = *(const f16x8*)(As + (m_off + 16 + r) * LDK + kq);
    f16x8 b0 = *(const f16x8*)(Bs + (n_off + r) * LDK + kq);
    f16x8 b1 = *(const f16x8*)(Bs + (n_off + 16 + r) * LDK + kq);
    acc[0][0] = __builtin_amdgcn_mfma_f32_16x16x32_f16(a0, b0, acc[0][0], 0, 0, 0);
    acc[0][1] = __builtin_amdgcn_mfma_f32_16x16x32_f16(a0, b1, acc[0][1], 0, 0, 0);
    acc[1][0] = __builtin_amdgcn_mfma_f32_16x16x32_f16(a1, b0, acc[1][0], 0, 0, 0);
    acc[1][1] = __builtin_amdgcn_mfma_f32_16x16x32_f16(a1, b1, acc[1][1], 0, 0, 0);
}

#define GEMM_PROLOGUE()                                         \
    __shared__ f16 As[64 * LDK];                                \
    __shared__ f16 Bs[64 * LDK];                                \
    const int w = threadIdx.x >> 6;                             \
    const int m_off = (w & 1) * 32, n_off = (w >> 1) * 32;      \
    const int lane = threadIdx.x & 63;                          \
    f32x4 zero = {0.f, 0.f, 0.f, 0.f};                          \
    f32x4 acc[2][2] = {{zero, zero}, {zero, zero}};

// ---- convert all fp32 inputs/weights to f16 once ----
// dst layout (f16 elems): q[4M] k[4M] v[4M] pe[1M] Wq[1M] Wk[1M] Wv[1M] Wp[1M] Wo[1M]
__global__ __launch_bounds__(256) void cvt_all(
    const float* __restrict__ q, const float* __restrict__ k, const float* __restrict__ v,
    const float* __restrict__ pe, const float* __restrict__ Wq, const float* __restrict__ Wk,
    const float* __restrict__ Wv, const float* __restrict__ Wp, const float* __restrict__ Wo,
    f16* __restrict__ dst) {
    const int seg = blockIdx.y;
    const float* srcs[9] = {q, k, v, pe, Wq, Wk, Wv, Wp, Wo};
    const int sz = (seg < 3) ? 4194304 : 1048576;
    const size_t off = (seg < 3) ? (size_t)seg * 4194304
                                 : (size_t)12582912 + (size_t)(seg - 3) * 1048576;
    const size_t i0 = ((size_t)blockIdx.x * 256 + threadIdx.x) * 16;
    if (i0 >= (size_t)sz) return;
    const float* s = srcs[seg] + i0;
    f16* d = dst + off + i0;
#pragma unroll
    for (int half = 0; half < 2; ++half) {
        float4 u = *(const float4*)(s + half * 8);
        float4 w = *(const float4*)(s + half * 8 + 4);
        f16x8 h;
        h[0] = (f16)u.x; h[1] = (f16)u.y; h[2] = (f16)u.z; h[3] = (f16)u.w;
        h[4] = (f16)w.x; h[5] = (f16)w.y; h[6] = (f16)w.z; h[7] = (f16)w.w;
        *(f16x8*)(d + half * 8) = h;
    }
}

// ---- batched Q/K/V projection: grid.z selects which ----
__global__ __launch_bounds__(256) void proj_qkv(
    const f16* __restrict__ qf, const f16* __restrict__ kf, const f16* __restrict__ vf,
    const f16* __restrict__ Wqf, const f16* __restrict__ Wkf, const f16* __restrict__ Wvf,
    const float* __restrict__ bq, const float* __restrict__ bk, const float* __restrict__ bv,
    const float* __restrict__ pbu, const float* __restrict__ pbv,
    f16* __restrict__ q_u, f16* __restrict__ q_v, f16* __restrict__ kh,
    f16* __restrict__ vh) {
    GEMM_PROLOGUE();
    const int z = blockIdx.z;
    const f16* A = (z == 0) ? qf : (z == 1) ? kf : vf;
    const f16* W = (z == 0) ? Wqf : (z == 1) ? Wkf : Wvf;
    const float* bias = (z == 0) ? bq : (z == 1) ? bk : bv;
    const int m0 = blockIdx.y * 64, n0 = blockIdx.x * 64;
    for (int k0 = 0; k0 < 1024; k0 += 32) {
        stage_f16g(A + (size_t)m0 * 1024 + k0, 1024, As);
        stage_f16g(W + (size_t)n0 * 1024 + k0, 1024, Bs);
        __syncthreads();
        mma_step(As, Bs, m_off, n_off, acc);
        __syncthreads();
    }
#pragma unroll
    for (int mt = 0; mt < 2; ++mt)
#pragma unroll
        for (int nt = 0; nt < 2; ++nt)
#pragma unroll
            for (int rr = 0; rr < 4; ++rr) {
                int m = m0 + m_off + mt * 16 + (lane >> 4) * 4 + rr;
                int n = n0 + n_off + nt * 16 + (lane & 15);
                float base = acc[mt][nt][rr] + bias[n];
                int b = m >> 10, t = m & 1023, h = n >> 6, d = n & 63;
                size_t idx = ((size_t)((b * 16 + h) * 1024 + t)) * 64 + d;
                if (z == 0) {
                    q_u[idx] = (f16)(base + pbu[n]);
                    q_v[idx] = (f16)(base + pbv[n]);
                } else if (z == 1) {
                    kh[idx] = (f16)base;
                } else {
                    vh[idx] = (f16)base;
                }
            }
}

// ---- P projection (no bias): pp[h][pos][64] ----
__global__ __launch_bounds__(256) void proj_p(const f16* __restrict__ A,
                                              const f16* __restrict__ W,
                                              f16* __restrict__ o1) {
    GEMM_PROLOGUE();
    const int m0 = blockIdx.y * 64;
    const int n0 = blockIdx.x * 64;
    for (int k0 = 0; k0 < 1024; k0 += 32) {
        stage_f16g(A + (size_t)m0 * 1024 + k0, 1024, As);
        stage_f16g(W + (size_t)n0 * 1024 + k0, 1024, Bs);
        __syncthreads();
        mma_step(As, Bs, m_off, n_off, acc);
        __syncthreads();
    }
#pragma unroll
    for (int mt = 0; mt < 2; ++mt)
#pragma unroll
        for (int nt = 0; nt < 2; ++nt)
#pragma unroll
            for (int rr = 0; rr < 4; ++rr) {
                int m = m0 + m_off + mt * 16 + (lane >> 4) * 4 + rr;
                int n = n0 + n_off + nt * 16 + (lane & 15);
                int h = n >> 6, d = n & 63;
                o1[((size_t)h * 1024 + m) * 64 + d] = (f16)acc[mt][nt][rr];
            }
}

// BD = q_v @ p[h]^T per (b,h); epilogue writes rel_shift-ed positions.
__global__ __launch_bounds__(256) void bd_gemm(const f16* __restrict__ qv,
                                               const f16* __restrict__ p,
                                               f16* __restrict__ bds) {
    GEMM_PROLOGUE();
    const int bh = blockIdx.z;
    const int h = bh & 15;
    const int m0 = blockIdx.y * 64, n0 = blockIdx.x * 64;
    const f16* Ab = qv + (size_t)bh * 65536;
    const f16* Bb = p + (size_t)h * 65536;
    for (int k0 = 0; k0 < 64; k0 += 32) {
        stage_f16g(Ab + (size_t)m0 * 64 + k0, 64, As);
        stage_f16g(Bb + (size_t)n0 * 64 + k0, 64, Bs);
        __syncthreads();
        mma_step(As, Bs, m_off, n_off, acc);
        __syncthreads();
    }
    f16* B0 = bds + (size_t)bh * 1048576;
#pragma unroll
    for (int mt = 0; mt < 2; ++mt)
#pragma unroll
        for (int nt = 0; nt < 2; ++nt)
#pragma unroll
            for (int rr = 0; rr < 4; ++rr) {
                int r = m0 + m_off + mt * 16 + (lane >> 4) * 4 + rr;
                int c = n0 + n_off + nt * 16 + (lane & 15);
                float vv = acc[mt][nt][rr];
                if (c >= 1023 - r) {
                    B0[(size_t)r * 1024 + (c + r - 1023)] = (f16)vv;
                } else if (r >= 1) {
                    B0[(size_t)(r - 1) * 1024 + (c + r + 1)] = (f16)vv;
                }
            }
}

// AC = q_u @ kh^T per (b,h); adds shifted-BD (diag j==i+1 is 0), scales, in place.
__global__ __launch_bounds__(256) void ac_gemm(const f16* __restrict__ qu,
                                               const f16* __restrict__ kh,
                                               f16* __restrict__ bds) {
    GEMM_PROLOGUE();
    const int bh = blockIdx.z;
    const int m0 = blockIdx.y * 64, n0 = blockIdx.x * 64;
    const f16* Ab = qu + (size_t)bh * 65536;
    const f16* Bb = kh + (size_t)bh * 65536;
    for (int k0 = 0; k0 < 64; k0 += 32) {
        stage_f16g(Ab + (size_t)m0 * 64 + k0, 64, As);
        stage_f16g(Bb + (size_t)n0 * 64 + k0, 64, Bs);
        __syncthreads();
        mma_step(As, Bs, m_off, n_off, acc);
        __syncthreads();
    }
#pragma unroll
    for (int mt = 0; mt < 2; ++mt)
#pragma unroll
        for (int nt = 0; nt < 2; ++nt)
#pragma unroll
            for (int rr = 0; rr < 4; ++rr) {
                int i = m0 + m_off + mt * 16 + (lane >> 4) * 4 + rr;
                int j = n0 + n_off + nt * 16 + (lane & 15);
                size_t idx = (size_t)bh * 1048576 + (size_t)i * 1024 + j;
                float bdv = (j == i + 1) ? 0.f : (float)bds[idx];
                bds[idx] = (f16)((acc[mt][nt][rr] + bdv) * 0.125f);
            }
}

// ---- fused softmax + PV ----
// grid: (16 row-tiles, 64 bh). Pass 1: per-row max & sum (streaming).
// Pass 2: per 32-col tile: p = exp(s-m)/l -> attn (fp32) + LDS -> MFMA with V^T.
__global__ __launch_bounds__(256) void softmax_pv(const f16* __restrict__ scores,
                                                  const int* __restrict__ mask,
                                                  const f16* __restrict__ vh,
                                                  float* __restrict__ attn,
                                                  f16* __restrict__ oh) {
    const int bh = blockIdx.y;
    const int i0 = blockIdx.x * 64;
    const int b = bh >> 4, h = bh & 15;
    const f16* S = scores + (size_t)bh * 1048576 + (size_t)i0 * 1024;
    const int* MK = mask + ((size_t)b * 1024 + i0) * 1024;
    __shared__ float s_max[64], s_invl[64];

    const int w = threadIdx.x >> 6;
    const int lane = threadIdx.x & 63;

    // pass 1: wave w handles rows w*16 .. w*16+15; lane covers 16 cols
    for (int rr = 0; rr < 16; ++rr) {
        int r = w * 16 + rr;
        const f16* srow = S + (size_t)r * 1024 + lane * 16;
        const int* mrow = MK + (size_t)r * 1024 + lane * 16;
        f16x8 a0 = *(const f16x8*)srow;
        f16x8 a1 = *(const f16x8*)(srow + 8);
        int4 m0 = *(const int4*)mrow;
        int4 m1 = *(const int4*)(mrow + 4);
        int4 m2 = *(const int4*)(mrow + 8);
        int4 m3 = *(const int4*)(mrow + 12);
        int mks[16] = {m0.x, m0.y, m0.z, m0.w, m1.x, m1.y, m1.z, m1.w,
                       m2.x, m2.y, m2.z, m2.w, m3.x, m3.y, m3.z, m3.w};
        float vals[16];
        float mx = -1e30f;
#pragma unroll
        for (int j = 0; j < 16; ++j) {
            float v = (j < 8) ? (float)a0[j] : (float)a1[j - 8];
            if (mks[j] == 0) v = -10000.0f;
            vals[j] = v;
            mx = fmaxf(mx, v);
        }
#pragma unroll
        for (int off = 32; off > 0; off >>= 1) mx = fmaxf(mx, __shfl_xor(mx, off));
        float sum = 0.f;
#pragma unroll
        for (int j = 0; j < 16; ++j) sum += __expf(vals[j] - mx);
#pragma unroll
        for (int off = 32; off > 0; off >>= 1) sum += __shfl_xor(sum, off);
        if (lane == 0) {
            s_max[r] = mx;
            s_invl[r] = 1.f / sum;
        }
    }
    __syncthreads();

    // pass 2: PV with on-the-fly probability computation
    __shared__ f16 As[64 * LDK];
    __shared__ f16 Bs[64 * LDK];
    const int m_off = (w & 1) * 32, n_off = (w >> 1) * 32;
    f32x4 zero = {0.f, 0.f, 0.f, 0.f};
    f32x4 acc[2][2] = {{zero, zero}, {zero, zero}};
    const int r2 = threadIdx.x >> 2;
    const int c2 = (threadIdx.x & 3) * 8;
    const f16* Vb = vh + (size_t)bh * 65536;
    float* arow = attn + (size_t)bh * 1048576 + (size_t)(i0 + r2) * 1024 + c2;

    for (int j0 = 0; j0 < 1024; j0 += 32) {
        f16x8 sv = *(const f16x8*)(S + (size_t)r2 * 1024 + j0 + c2);
        const int* mp = MK + (size_t)r2 * 1024 + j0 + c2;
        int4 mk0 = *(const int4*)mp;
        int4 mk1 = *(const int4*)(mp + 4);
        int mks[8] = {mk0.x, mk0.y, mk0.z, mk0.w, mk1.x, mk1.y, mk1.z, mk1.w};
        float mx = s_max[r2], il = s_invl[r2];
        f16x8 pv;
        float po[8];
#pragma unroll
        for (int j = 0; j < 8; ++j) {
            float s = (float)sv[j];
            if (mks[j] == 0) s = -10000.0f;
            float p = __expf(s - mx) * il;
            po[j] = p;
            pv[j] = (f16)p;
        }
        *(float4*)(arow + j0) = {po[0], po[1], po[2], po[3]};
        *(float4*)(arow + j0 + 4) = {po[4], po[5], po[6], po[7]};
        *(f16x8*)(As + r2 * LDK + c2) = pv;
        stage_vT(Vb + (size_t)j0 * 64, Bs);
        __syncthreads();
        mma_step(As, Bs, m_off, n_off, acc);
        __syncthreads();
    }

#pragma unroll
    for (int mt = 0; mt < 2; ++mt)
#pragma unroll
        for (int nt = 0; nt < 2; ++nt)
#pragma unroll
            for (int rr = 0; rr < 4; ++rr) {
                int t = i0 + m_off + mt * 16 + (lane >> 4) * 4 + rr;
                int d = n_off + nt * 16 + (lane & 15);
                oh[((size_t)(b * 1024 + t)) * 1024 + h * 64 + d] =
                    (f16)acc[mt][nt][rr];
            }
}

// output = concat @ Wo^T + bo (fp32 out)
__global__ __launch_bounds__(256) void out_gemm(const f16* __restrict__ A,
                                                const f16* __restrict__ W,
                                                const float* __restrict__ bias,
                                                float* __restrict__ out) {
    GEMM_PROLOGUE();
    const int m0 = blockIdx.y * 64;
    const int n0 = blockIdx.x * 64;
    for (int k0 = 0; k0 < 1024; k0 += 32) {
        stage_f16g(A + (size_t)m0 * 1024 + k0, 1024, As);
        stage_f16g(W + (size_t)n0 * 1024 + k0, 1024, Bs);
        __syncthreads();
        mma_step(As, Bs, m_off, n_off, acc);
        __syncthreads();
    }
#pragma unroll
    for (int mt = 0; mt < 2; ++mt)
#pragma unroll
        for (int nt = 0; nt < 2; ++nt)
#pragma unroll
            for (int rr = 0; rr < 4; ++rr) {
                int m = m0 + m_off + mt * 16 + (lane >> 4) * 4 + rr;
                int n = n0 + n_off + nt * 16 + (lane & 15);
                out[(size_t)m * 1024 + n] = acc[mt][nt][rr] + bias[n];
            }
}

extern "C" void kernel_launch(void* const* d_in, const int* in_sizes, int n_in,
                              void* d_out, int out_size, void* d_ws, size_t ws_size,
                              hipStream_t stream) {
    (void)in_sizes; (void)n_in; (void)out_size; (void)ws_size;
    const float* q   = (const float*)d_in[0];
    const float* k   = (const float*)d_in[1];
    const float* v   = (const float*)d_in[2];
    const float* pe  = (const float*)d_in[3];
    const int*   msk = (const int*)d_in[4];
    const float* Wq  = (const float*)d_in[5];
    const float* bq  = (const float*)d_in[6];
    const float* Wk  = (const float*)d_in[7];
    const float* bk  = (const float*)d_in[8];
    const float* Wv  = (const float*)d_in[9];
    const float* bv  = (const float*)d_in[10];
    const float* Wp  = (const float*)d_in[11];
    const float* pbu = (const float*)d_in[12];
    const float* pbv = (const float*)d_in[13];
    const float* Wo  = (const float*)d_in[14];
    const float* bo  = (const float*)d_in[15];

    char* ws = (char*)d_ws;
    f16* cvt = (f16*)(ws + 0);  // 36 MB: q,k,v,pe,Wq,Wk,Wv,Wp,Wo in f16
    f16* qf  = cvt;
    f16* kf  = cvt + 4194304;
    f16* vf  = cvt + 8388608;
    f16* pef = cvt + 12582912;
    f16* Wqf = cvt + 13631488;
    f16* Wkf = cvt + 14680064;
    f16* Wvf = cvt + 15728640;
    f16* Wpf = cvt + 16777216;
    f16* Wof = cvt + 17825792;

    f16* q_u = (f16*)(ws + 37748736);   //  8 MB  [b][h][t][64]
    f16* q_v = (f16*)(ws + 46137344);   //  8 MB
    f16* kh  = (f16*)(ws + 54525952);   //  8 MB
    f16* vh  = (f16*)(ws + 62914560);   //  8 MB
    f16* pp  = (f16*)(ws + 71303168);   //  2 MB  [h][pos][64]
    f16* bds = (f16*)(ws + 73400320);   // 128 MB [b][h][t][s] (shifted BD -> scores)
    f16* oh  = (f16*)(ws + 207618048);  //  8 MB  [b][t][h*64+d]

    float* out  = (float*)d_out;
    float* attn = out + 4194304;

    dim3 blk(256);
    cvt_all<<<dim3(1024, 9), blk, 0, stream>>>(q, k, v, pe, Wq, Wk, Wv, Wp, Wo, cvt);
    proj_qkv<<<dim3(16, 64, 3), blk, 0, stream>>>(qf, kf, vf, Wqf, Wkf, Wvf, bq, bk, bv,
                                                  pbu, pbv, q_u, q_v, kh, vh);
    proj_p<<<dim3(16, 16), blk, 0, stream>>>(pef, Wpf, pp);
    bd_gemm<<<dim3(16, 16, 64), blk, 0, stream>>>(q_v, pp, bds);
    ac_gemm<<<dim3(16, 16, 64), blk, 0, stream>>>(q_u, kh, bds);
    softmax_pv<<<dim3(16, 64), blk, 0, stream>>>(bds, msk, vh, attn, oh);
    out_gemm<<<dim3(16, 64), blk, 0, stream>>>(oh, Wof, bo, out);
}